// Round 1
// baseline (387.490 us; speedup 1.0000x reference)
//
#include <hip/hip_runtime.h>
#include <hip/hip_bf16.h>
#include <cstdint>

// SelfAttention: B=8, S=2048, D_IN=D_OUT=768, fp32 in/out.
// Pipeline (all bf16 MFMA, fp32 accumulate):
//   1. xb = bf16(x)                      [16384][768]
//   2. Wt[e][n][k] = bf16(QKV[e][k][n])  [3][768][768]
//   3. qkvb = xb @ Wt^T                  [16384][2304]  (Q|K|V fused, bf16)
//   4. vt[b][d][s] = V[b][s][d]          [8][768][2048] (bf16)
//   5. logits = scale * Q K^T            [8][2048][2048] bf16 (scratch)
//   6. row softmax in place (fp32 math)
//   7. out = P @ vt^T                    fp32 -> d_out
// ws layout (bytes): xb 25.2M | Wt 3.5M | qkvb 75.5M | vt 25.2M | probs 67.1M
// total ~196.5 MB.

#define NB 8
#define NS 2048
#define ND 768
#define NQKV 2304
#define MTOT 16384  // NB*NS

using f32x4 = __attribute__((ext_vector_type(4))) float;
using s16x8 = __attribute__((ext_vector_type(8))) short;

struct alignas(16) bf16x8 { __hip_bfloat16 h[8]; };
struct alignas(8)  bf16x4 { __hip_bfloat16 h[4]; };

// ---------------- pass 1: x fp32 -> bf16 ----------------
__global__ __launch_bounds__(256) void convert_x_kernel(const float* __restrict__ x,
                                                        __hip_bfloat16* __restrict__ xb) {
    const int i = blockIdx.x * 256 + threadIdx.x;  // over float4 groups (divisible)
    const float4 v = ((const float4*)x)[i];
    bf16x4 o;
    o.h[0] = __float2bfloat16(v.x);
    o.h[1] = __float2bfloat16(v.y);
    o.h[2] = __float2bfloat16(v.z);
    o.h[3] = __float2bfloat16(v.w);
    ((bf16x4*)xb)[i] = o;
}

// ---------------- pass 2: W[e][k][n] fp32 -> Wt[e][n][k] bf16 ----------------
__global__ __launch_bounds__(256) void transpose_w_kernel(const float* __restrict__ W,
                                                          __hip_bfloat16* __restrict__ Wt) {
    __shared__ float tile[32][33];
    const int e = blockIdx.z;
    const int k0 = blockIdx.y * 32, n0 = blockIdx.x * 32;
    const float* Wp = W + (size_t)e * ND * ND;
    __hip_bfloat16* Wo = Wt + (size_t)e * ND * ND;
    for (int r = threadIdx.y; r < 32; r += 8)
        tile[r][threadIdx.x] = Wp[(k0 + r) * ND + n0 + threadIdx.x];
    __syncthreads();
    for (int r = threadIdx.y; r < 32; r += 8)
        Wo[(long)(n0 + r) * ND + k0 + threadIdx.x] = __float2bfloat16(tile[threadIdx.x][r]);
}

// ---------------- pass 4: V[b][s][d] -> vt[b][d][s] (bf16) ----------------
__global__ __launch_bounds__(256) void transpose_v_kernel(const __hip_bfloat16* __restrict__ qkv,
                                                          __hip_bfloat16* __restrict__ vt) {
    __shared__ __hip_bfloat16 tile[32][33];
    const int b = blockIdx.z;
    const int s0 = blockIdx.y * 32, d0 = blockIdx.x * 32;
    for (int r = threadIdx.y; r < 32; r += 8)
        tile[r][threadIdx.x] = qkv[(long)(b * NS + s0 + r) * NQKV + 1536 + d0 + threadIdx.x];
    __syncthreads();
    for (int r = threadIdx.y; r < 32; r += 8)
        vt[((long)b * ND + d0 + r) * NS + s0 + threadIdx.x] = tile[threadIdx.x][r];
}

// ---------------- MFMA GEMM: C[m][n] = scale * sum_k A[m][k]*B[n][k] ----------------
// m97 structure: 128x128 tile, BK=32, 4 waves, 4x4 16x16x32 MFMAs/wave,
// global_load_lds width=16 staging (LDS dest = wave base + lane*16, no padding).
__device__ __forceinline__ void storeC(float* p, float v) { *p = v; }
__device__ __forceinline__ void storeC(__hip_bfloat16* p, float v) { *p = __float2bfloat16(v); }

template <typename OutT>
__global__ __launch_bounds__(256) void gemm_bt_kernel(
    const __hip_bfloat16* __restrict__ A,   // [M][lda], k-contiguous
    const __hip_bfloat16* __restrict__ Bm,  // [N][ldb], k-contiguous
    OutT* __restrict__ C,                   // [M][ldc]
    int K, int lda, int ldb, int ldc,
    long sA, long sB, long sC, float scale) {
    __shared__ __hip_bfloat16 As[128 * 32];
    __shared__ __hip_bfloat16 Bs[128 * 32];

    const int b = blockIdx.z;
    A  += (long)b * sA;
    Bm += (long)b * sB;
    C  += (long)b * sC;
    const int tileM = blockIdx.y * 128;
    const int tileN = blockIdx.x * 128;

    const int tid  = threadIdx.x;
    const int lane = tid & 63;
    const int wave = tid >> 6;
    const int wm = (wave >> 1) * 64;  // wave row offset in tile
    const int wn = (wave & 1) * 64;   // wave col offset in tile
    const int quad = lane >> 4;
    const int lrow = lane & 15;

    // staging coords: thread covers 16B; A-tile (8KB) = 2 chunks of 4KB
    const int srow = tid >> 2;        // 0..63
    const int scol = (tid & 3) << 3;  // 0,8,16,24 (bf16 elems)

    f32x4 acc[4][4];
    const f32x4 zero = {0.f, 0.f, 0.f, 0.f};
#pragma unroll
    for (int i = 0; i < 4; ++i)
#pragma unroll
        for (int j = 0; j < 4; ++j) acc[i][j] = zero;

    const __hip_bfloat16* gA = A + (long)(tileM + srow) * lda + scol;
    const __hip_bfloat16* gB = Bm + (long)(tileN + srow) * ldb + scol;
    char* AsB = (char*)As;
    char* BsB = (char*)Bs;
    const int ldsOff = tid * 16;  // bytes

    typedef const __attribute__((address_space(1))) void* gp;
    typedef __attribute__((address_space(3))) void* sp;

    for (int k0 = 0; k0 < K; k0 += 32) {
        __syncthreads();  // prior iteration's ds_reads done before overwrite
        __builtin_amdgcn_global_load_lds((gp)(gA + k0),                (sp)(AsB + ldsOff),        16, 0, 0);
        __builtin_amdgcn_global_load_lds((gp)(gA + (long)64 * lda + k0), (sp)(AsB + 4096 + ldsOff), 16, 0, 0);
        __builtin_amdgcn_global_load_lds((gp)(gB + k0),                (sp)(BsB + ldsOff),        16, 0, 0);
        __builtin_amdgcn_global_load_lds((gp)(gB + (long)64 * ldb + k0), (sp)(BsB + 4096 + ldsOff), 16, 0, 0);
        __syncthreads();  // compiler drains vmcnt before barrier

        s16x8 af[4], bfr[4];
#pragma unroll
        for (int i = 0; i < 4; ++i)
            af[i] = *(const s16x8*)(AsB + ((wm + i * 16 + lrow) * 32 + quad * 8) * 2);
#pragma unroll
        for (int j = 0; j < 4; ++j)
            bfr[j] = *(const s16x8*)(BsB + ((wn + j * 16 + lrow) * 32 + quad * 8) * 2);
#pragma unroll
        for (int i = 0; i < 4; ++i)
#pragma unroll
            for (int j = 0; j < 4; ++j)
                acc[i][j] = __builtin_amdgcn_mfma_f32_16x16x32_bf16(af[i], bfr[j], acc[i][j], 0, 0, 0);
    }

    // epilogue: D[row=quad*4+r][col=lane&15] per 16x16 tile (verified m89/m91)
#pragma unroll
    for (int i = 0; i < 4; ++i) {
#pragma unroll
        for (int j = 0; j < 4; ++j) {
            const int col = tileN + wn + j * 16 + lrow;
#pragma unroll
            for (int r = 0; r < 4; ++r) {
                const int row = tileM + wm + i * 16 + quad * 4 + r;
                storeC(C + (long)row * ldc + col, acc[i][j][r] * scale);
            }
        }
    }
}

// ---------------- pass 6: row softmax in place over 2048 bf16 ----------------
__global__ __launch_bounds__(256) void softmax_kernel(__hip_bfloat16* __restrict__ P) {
    __shared__ float redmax[4];
    __shared__ float redsum[4];
    const long row = blockIdx.x;
    __hip_bfloat16* p = P + row * NS;
    const int tid = threadIdx.x;
    const int lane = tid & 63, wave = tid >> 6;

    bf16x8 raw = *(const bf16x8*)(p + tid * 8);
    float v[8];
#pragma unroll
    for (int i = 0; i < 8; ++i) v[i] = __bfloat162float(raw.h[i]);

    float m = v[0];
#pragma unroll
    for (int i = 1; i < 8; ++i) m = fmaxf(m, v[i]);
    for (int off = 32; off > 0; off >>= 1) m = fmaxf(m, __shfl_down(m, off));
    if (lane == 0) redmax[wave] = m;
    __syncthreads();
    m = fmaxf(fmaxf(redmax[0], redmax[1]), fmaxf(redmax[2], redmax[3]));

    float s = 0.f;
#pragma unroll
    for (int i = 0; i < 8; ++i) {
        v[i] = __expf(v[i] - m);
        s += v[i];
    }
    for (int off = 32; off > 0; off >>= 1) s += __shfl_down(s, off);
    if (lane == 0) redsum[wave] = s;
    __syncthreads();
    s = redsum[0] + redsum[1] + redsum[2] + redsum[3];
    const float inv = 1.f / s;

    bf16x8 o;
#pragma unroll
    for (int i = 0; i < 8; ++i) o.h[i] = __float2bfloat16(v[i] * inv);
    *(bf16x8*)(p + tid * 8) = o;
}

// ---------------- launch ----------------
extern "C" void kernel_launch(void* const* d_in, const int* in_sizes, int n_in,
                              void* d_out, int out_size, void* d_ws, size_t ws_size,
                              hipStream_t stream) {
    const float* x   = (const float*)d_in[0];  // [8][2048][768]
    const float* QKV = (const float*)d_in[1];  // [3][768][768]
    float* out = (float*)d_out;                // [8][2048][768]

    uint8_t* ws = (uint8_t*)d_ws;
    constexpr size_t XB_BYTES  = (size_t)MTOT * ND * 2;      // 25,165,824
    constexpr size_t WT_BYTES  = (size_t)3 * ND * ND * 2;    //  3,538,944
    constexpr size_t QKV_BYTES = (size_t)MTOT * NQKV * 2;    // 75,497,472
    constexpr size_t VT_BYTES  = (size_t)NB * ND * NS * 2;   // 25,165,824
    __hip_bfloat16* xb    = (__hip_bfloat16*)(ws);
    __hip_bfloat16* Wt    = (__hip_bfloat16*)(ws + XB_BYTES);
    __hip_bfloat16* qkvb  = (__hip_bfloat16*)(ws + XB_BYTES + WT_BYTES);
    __hip_bfloat16* vt    = (__hip_bfloat16*)(ws + XB_BYTES + WT_BYTES + QKV_BYTES);
    __hip_bfloat16* probs = (__hip_bfloat16*)(ws + XB_BYTES + WT_BYTES + QKV_BYTES + VT_BYTES);

    const float scale = 0.03608439182435161f;  // 1/sqrt(768)

    // 1. x -> bf16
    convert_x_kernel<<<MTOT * ND / 1024, 256, 0, stream>>>(x, xb);
    // 2. W -> Wt (bf16, [n][k])
    transpose_w_kernel<<<dim3(ND / 32, ND / 32, 3), dim3(32, 8), 0, stream>>>(QKV, Wt);
    // 3. fused QKV projection: [16384][2304] bf16
    gemm_bt_kernel<__hip_bfloat16><<<dim3(NQKV / 128, MTOT / 128, 1), 256, 0, stream>>>(
        xb, Wt, qkvb, ND, ND, ND, NQKV, 0, 0, 0, 1.0f);
    // 4. vt[b][d][s]
    transpose_v_kernel<<<dim3(ND / 32, NS / 32, NB), dim3(32, 8), 0, stream>>>(qkvb, vt);
    // 5. logits = scale * Q K^T  (per batch)
    gemm_bt_kernel<__hip_bfloat16><<<dim3(NS / 128, NS / 128, NB), 256, 0, stream>>>(
        qkvb, qkvb + 768, probs, ND, NQKV, NQKV, NS,
        (long)NS * NQKV, (long)NS * NQKV, (long)NS * NS, scale);
    // 6. softmax rows in place
    softmax_kernel<<<MTOT, 256, 0, stream>>>(probs);
    // 7. out = P @ V  (fp32 out)
    gemm_bt_kernel<float><<<dim3(ND / 128, NS / 128, NB), 256, 0, stream>>>(
        probs, vt, out, NS, NS, NS, ND,
        (long)NS * NS, (long)ND * NS, (long)NS * ND, 1.0f);
}

// Round 2
// 313.919 us; speedup vs baseline: 1.2344x; 1.2344x over previous
//
#include <hip/hip_runtime.h>
#include <hip/hip_bf16.h>
#include <cstdint>

// SelfAttention: B=8, S=2048, D_IN=D_OUT=768, fp32 in/out.
// R2: GEMM gets BK=64 (half the barrier drains) + XOR-swizzled LDS
// (kills the 7.08M bank conflicts/dispatch seen in R1), batch-on-x grid
// swizzle for per-XCD L2 locality, wave-per-row softmax (no barriers).
// ws layout: xb 25.2M | Wt 3.5M | qkvb 75.5M | vt 25.2M | probs 67.1M  (~196.5 MB)

#define NB 8
#define NS 2048
#define ND 768
#define NQKV 2304
#define MTOT 16384  // NB*NS

using f32x4 = __attribute__((ext_vector_type(4))) float;
using s16x8 = __attribute__((ext_vector_type(8))) short;

struct alignas(16) bf16x8 { __hip_bfloat16 h[8]; };
struct alignas(8)  bf16x4 { __hip_bfloat16 h[4]; };

// ---------------- pass 1: x fp32 -> bf16 ----------------
__global__ __launch_bounds__(256) void convert_x_kernel(const float* __restrict__ x,
                                                        __hip_bfloat16* __restrict__ xb) {
    const int i = blockIdx.x * 256 + threadIdx.x;
    const float4 v = ((const float4*)x)[i];
    bf16x4 o;
    o.h[0] = __float2bfloat16(v.x);
    o.h[1] = __float2bfloat16(v.y);
    o.h[2] = __float2bfloat16(v.z);
    o.h[3] = __float2bfloat16(v.w);
    ((bf16x4*)xb)[i] = o;
}

// ---------------- pass 2: W[e][k][n] fp32 -> Wt[e][n][k] bf16 ----------------
__global__ __launch_bounds__(256) void transpose_w_kernel(const float* __restrict__ W,
                                                          __hip_bfloat16* __restrict__ Wt) {
    __shared__ float tile[32][33];
    const int e = blockIdx.z;
    const int k0 = blockIdx.y * 32, n0 = blockIdx.x * 32;
    const float* Wp = W + (size_t)e * ND * ND;
    __hip_bfloat16* Wo = Wt + (size_t)e * ND * ND;
    for (int r = threadIdx.y; r < 32; r += 8)
        tile[r][threadIdx.x] = Wp[(k0 + r) * ND + n0 + threadIdx.x];
    __syncthreads();
    for (int r = threadIdx.y; r < 32; r += 8)
        Wo[(long)(n0 + r) * ND + k0 + threadIdx.x] = __float2bfloat16(tile[threadIdx.x][r]);
}

// ---------------- pass 4: V[b][s][d] -> vt[b][d][s] (bf16) ----------------
__global__ __launch_bounds__(256) void transpose_v_kernel(const __hip_bfloat16* __restrict__ qkv,
                                                          __hip_bfloat16* __restrict__ vt) {
    __shared__ __hip_bfloat16 tile[32][33];
    const int b = blockIdx.z;
    const int s0 = blockIdx.y * 32, d0 = blockIdx.x * 32;
    for (int r = threadIdx.y; r < 32; r += 8)
        tile[r][threadIdx.x] = qkv[(long)(b * NS + s0 + r) * NQKV + 1536 + d0 + threadIdx.x];
    __syncthreads();
    for (int r = threadIdx.y; r < 32; r += 8)
        vt[((long)b * ND + d0 + r) * NS + s0 + threadIdx.x] = tile[threadIdx.x][r];
}

// ---------------- MFMA GEMM: C[m][n] = scale * sum_k A[m][k]*B[n][k] ----------------
// 128x128 tile, BK=64 (two 32-deep MFMA sub-iters per barrier pair), 4 waves,
// 4x4 16x16x32 MFMAs/wave, global_load_lds width=16 staging.
// LDS layout XOR-swizzled: row r, 16B-chunk slot c holds global chunk c^(r&7),
// so quad-group fragment reads spread over 8 chunk positions (2-way max = free).
__device__ __forceinline__ void storeC(float* p, float v) { *p = v; }
__device__ __forceinline__ void storeC(__hip_bfloat16* p, float v) { *p = __float2bfloat16(v); }

template <typename OutT, bool BATCH_X>
__global__ __launch_bounds__(256, 3) void gemm_bt_kernel(
    const __hip_bfloat16* __restrict__ A,   // [M][lda], k-contiguous
    const __hip_bfloat16* __restrict__ Bm,  // [N][ldb], k-contiguous
    OutT* __restrict__ C,                   // [M][ldc]
    int K, int lda, int ldb, int ldc,
    long sA, long sB, long sC, float scale) {
    __shared__ __hip_bfloat16 As[128 * 64];
    __shared__ __hip_bfloat16 Bs[128 * 64];

    int b, tileM, tileN;
    if (BATCH_X) {  // batch on x => batch == linear%8 == XCD id (L2 locality)
        b = blockIdx.x; tileN = blockIdx.y * 128; tileM = blockIdx.z * 128;
    } else {
        b = blockIdx.z; tileN = blockIdx.x * 128; tileM = blockIdx.y * 128;
    }
    A  += (long)b * sA;
    Bm += (long)b * sB;
    C  += (long)b * sC;

    const int tid  = threadIdx.x;
    const int lane = tid & 63;
    const int wave = tid >> 6;
    const int wm = (wave >> 1) * 64;
    const int wn = (wave & 1) * 64;
    const int quad = lane >> 4;
    const int lrow = lane & 15;

    // staging: thread covers 16B; row = tid>>3 (0..31), swizzled col chunk
    const int srow = tid >> 3;
    const int schunk = (tid & 7) ^ (srow & 7);  // global 16B-chunk this thread fetches
    const int scol = schunk << 3;               // bf16 elems

    f32x4 acc[4][4];
    const f32x4 zero = {0.f, 0.f, 0.f, 0.f};
#pragma unroll
    for (int i = 0; i < 4; ++i)
#pragma unroll
        for (int j = 0; j < 4; ++j) acc[i][j] = zero;

    const __hip_bfloat16* gA = A + (long)(tileM + srow) * lda + scol;
    const __hip_bfloat16* gB = Bm + (long)(tileN + srow) * ldb + scol;
    char* AsB = (char*)As;
    char* BsB = (char*)Bs;
    const int ldsOff = tid * 16;  // bytes; dest = wave-uniform base + lane*16

    typedef const __attribute__((address_space(1))) void* gp;
    typedef __attribute__((address_space(3))) void* sp;

    const int swa = (lrow & 7) << 4;  // XOR byte swizzle for fragment reads

    for (int k0 = 0; k0 < K; k0 += 64) {
        __syncthreads();
#pragma unroll
        for (int j = 0; j < 4; ++j)
            __builtin_amdgcn_global_load_lds((gp)(gA + (long)(j * 32) * lda + k0),
                                             (sp)(AsB + j * 4096 + ldsOff), 16, 0, 0);
#pragma unroll
        for (int j = 0; j < 4; ++j)
            __builtin_amdgcn_global_load_lds((gp)(gB + (long)(j * 32) * ldb + k0),
                                             (sp)(BsB + j * 4096 + ldsOff), 16, 0, 0);
        __syncthreads();

#pragma unroll
        for (int kk = 0; kk < 2; ++kk) {
            s16x8 af[4], bfr[4];
#pragma unroll
            for (int i = 0; i < 4; ++i)
                af[i] = *(const s16x8*)(AsB + (wm + i * 16 + lrow) * 128 +
                                        ((((kk << 2) | quad) << 4) ^ swa));
#pragma unroll
            for (int j = 0; j < 4; ++j)
                bfr[j] = *(const s16x8*)(BsB + (wn + j * 16 + lrow) * 128 +
                                         ((((kk << 2) | quad) << 4) ^ swa));
#pragma unroll
            for (int i = 0; i < 4; ++i)
#pragma unroll
                for (int j = 0; j < 4; ++j)
                    acc[i][j] = __builtin_amdgcn_mfma_f32_16x16x32_bf16(af[i], bfr[j], acc[i][j], 0, 0, 0);
        }
    }

    // epilogue: D[row=quad*4+r][col=lane&15] per 16x16 tile
#pragma unroll
    for (int i = 0; i < 4; ++i) {
#pragma unroll
        for (int j = 0; j < 4; ++j) {
            const int col = tileN + wn + j * 16 + lrow;
#pragma unroll
            for (int r = 0; r < 4; ++r) {
                const int row = tileM + wm + i * 16 + quad * 4 + r;
                storeC(C + (long)row * ldc + col, acc[i][j][r] * scale);
            }
        }
    }
}

// ---------------- pass 6: wave-per-row softmax over 2048 bf16, no barriers ----------------
__global__ __launch_bounds__(256) void softmax_kernel(__hip_bfloat16* __restrict__ P) {
    const long row = (long)blockIdx.x * 4 + (threadIdx.x >> 6);
    const int lane = threadIdx.x & 63;
    __hip_bfloat16* p = P + row * NS;

    bf16x8 raw[4];
    float v[32];
#pragma unroll
    for (int c = 0; c < 4; ++c) raw[c] = *(const bf16x8*)(p + c * 512 + lane * 8);
#pragma unroll
    for (int c = 0; c < 4; ++c)
#pragma unroll
        for (int i = 0; i < 8; ++i) v[c * 8 + i] = __bfloat162float(raw[c].h[i]);

    float m = v[0];
#pragma unroll
    for (int i = 1; i < 32; ++i) m = fmaxf(m, v[i]);
#pragma unroll
    for (int off = 1; off < 64; off <<= 1) m = fmaxf(m, __shfl_xor(m, off));

    float s = 0.f;
#pragma unroll
    for (int i = 0; i < 32; ++i) {
        v[i] = __expf(v[i] - m);
        s += v[i];
    }
#pragma unroll
    for (int off = 1; off < 64; off <<= 1) s += __shfl_xor(s, off);
    const float inv = 1.f / s;

#pragma unroll
    for (int c = 0; c < 4; ++c) {
        bf16x8 o;
#pragma unroll
        for (int i = 0; i < 8; ++i) o.h[i] = __float2bfloat16(v[c * 8 + i] * inv);
        *(bf16x8*)(p + c * 512 + lane * 8) = o;
    }
}

// ---------------- launch ----------------
extern "C" void kernel_launch(void* const* d_in, const int* in_sizes, int n_in,
                              void* d_out, int out_size, void* d_ws, size_t ws_size,
                              hipStream_t stream) {
    const float* x   = (const float*)d_in[0];  // [8][2048][768]
    const float* QKV = (const float*)d_in[1];  // [3][768][768]
    float* out = (float*)d_out;                // [8][2048][768]

    uint8_t* ws = (uint8_t*)d_ws;
    constexpr size_t XB_BYTES  = (size_t)MTOT * ND * 2;
    constexpr size_t WT_BYTES  = (size_t)3 * ND * ND * 2;
    constexpr size_t QKV_BYTES = (size_t)MTOT * NQKV * 2;
    constexpr size_t VT_BYTES  = (size_t)NB * ND * NS * 2;
    __hip_bfloat16* xb    = (__hip_bfloat16*)(ws);
    __hip_bfloat16* Wt    = (__hip_bfloat16*)(ws + XB_BYTES);
    __hip_bfloat16* qkvb  = (__hip_bfloat16*)(ws + XB_BYTES + WT_BYTES);
    __hip_bfloat16* vt    = (__hip_bfloat16*)(ws + XB_BYTES + WT_BYTES + QKV_BYTES);
    __hip_bfloat16* probs = (__hip_bfloat16*)(ws + XB_BYTES + WT_BYTES + QKV_BYTES + VT_BYTES);

    const float scale = 0.03608439182435161f;  // 1/sqrt(768)

    // 1. x -> bf16
    convert_x_kernel<<<MTOT * ND / 1024, 256, 0, stream>>>(x, xb);
    // 2. W -> Wt (bf16, [n][k])
    transpose_w_kernel<<<dim3(ND / 32, ND / 32, 3), dim3(32, 8), 0, stream>>>(QKV, Wt);
    // 3. fused QKV projection: [16384][2304] bf16
    gemm_bt_kernel<__hip_bfloat16, false><<<dim3(NQKV / 128, MTOT / 128, 1), 256, 0, stream>>>(
        xb, Wt, qkvb, ND, ND, ND, NQKV, 0, 0, 0, 1.0f);
    // 4. vt[b][d][s]
    transpose_v_kernel<<<dim3(ND / 32, NS / 32, NB), dim3(32, 8), 0, stream>>>(qkvb, vt);
    // 5. logits = scale * Q K^T  (per batch; batch on x for XCD-L2 locality)
    gemm_bt_kernel<__hip_bfloat16, true><<<dim3(NB, NS / 128, NS / 128), 256, 0, stream>>>(
        qkvb, qkvb + 768, probs, ND, NQKV, NQKV, NS,
        (long)NS * NQKV, (long)NS * NQKV, (long)NS * NS, scale);
    // 6. softmax rows in place (wave per row)
    softmax_kernel<<<MTOT / 4, 256, 0, stream>>>(probs);
    // 7. out = P @ V  (fp32 out)
    gemm_bt_kernel<float, true><<<dim3(NB, ND / 128, NS / 128), 256, 0, stream>>>(
        probs, vt, out, NS, NS, NS, ND,
        (long)NS * NS, (long)ND * NS, (long)NS * ND, 1.0f);
}

// Round 3
// 289.345 us; speedup vs baseline: 1.3392x; 1.0849x over previous
//
#include <hip/hip_runtime.h>
#include <hip/hip_bf16.h>
#include <cstdint>

// SelfAttention: B=8, S=2048, D_IN=D_OUT=768, fp32 in/out.
// R3: kernel count 7->5. transpose_v folded into QKV-GEMM epilogue
// (V tiles bounce through XOR-swizzled LDS -> coalesced store to vt[b][d][s];
// V never written to qkvb, which shrinks to Q|K 1536 wide).
// convert_x + transpose_w merged into one preprocess kernel.
// GEMM core unchanged from R2 (BK=64, XOR-swizzled LDS, 0 bank conflicts,
// ~35% MfmaUtil = the documented m97-plateau for this K-loop shape).
// ws layout: xb 25.2M | Wt 3.5M | qkvb(QK) 50.3M | vt 25.2M | probs 67.1M

#define NB 8
#define NS 2048
#define ND 768
#define NQK 1536   // qkvb row width (Q|K only)
#define MTOT 16384 // NB*NS

using f32x4 = __attribute__((ext_vector_type(4))) float;
using s16x8 = __attribute__((ext_vector_type(8))) short;

struct alignas(16) bf16x8 { __hip_bfloat16 h[8]; };
struct alignas(8)  bf16x4 { __hip_bfloat16 h[4]; };

// ---------------- preprocess: convert x AND transpose W (one launch) ----------------
// blocks [0, 12288): xb = bf16(x), 1024 floats/block
// blocks [12288, 12288+1728): Wt[e][n][k] = bf16(W[e][k][n]), 32x32 tiles
#define CVT_BLOCKS 12288
__global__ __launch_bounds__(256) void preprocess_kernel(const float* __restrict__ x,
                                                         __hip_bfloat16* __restrict__ xb,
                                                         const float* __restrict__ W,
                                                         __hip_bfloat16* __restrict__ Wt) {
    __shared__ float tile[32][33];
    const int tid = threadIdx.x;
    if (blockIdx.x < CVT_BLOCKS) {
        const int i = blockIdx.x * 256 + tid;
        const float4 v = ((const float4*)x)[i];
        bf16x4 o;
        o.h[0] = __float2bfloat16(v.x);
        o.h[1] = __float2bfloat16(v.y);
        o.h[2] = __float2bfloat16(v.z);
        o.h[3] = __float2bfloat16(v.w);
        ((bf16x4*)xb)[i] = o;
    } else {
        const int bid = blockIdx.x - CVT_BLOCKS;       // 0..1727 = 3*24*24
        const int e = bid / 576, rem = bid % 576;
        const int k0 = (rem / 24) * 32, n0 = (rem % 24) * 32;
        const int tx = tid & 31, ty = tid >> 5;        // 32 x 8
        const float* Wp = W + (size_t)e * ND * ND;
        __hip_bfloat16* Wo = Wt + (size_t)e * ND * ND;
        for (int r = ty; r < 32; r += 8)
            tile[r][tx] = Wp[(k0 + r) * ND + n0 + tx];
        __syncthreads();
        for (int r = ty; r < 32; r += 8)
            Wo[(long)(n0 + r) * ND + k0 + tx] = __float2bfloat16(tile[tx][r]);
    }
}

// ---------------- MFMA GEMM: C[m][n] = scale * sum_k A[m][k]*B[n][k] ----------------
// 128x128 tile, BK=64, 4 waves, 4x4 16x16x32 MFMAs/wave, global_load_lds
// width=16 staging, XOR-swizzled LDS (0 bank conflicts, measured R2).
// EPI: 0 = bf16 C, 1 = f32 C, 2 = QKV split (tileN<1536 -> bf16 C; else
// transpose tile through LDS and store to vt[b][d][s]).
__device__ __forceinline__ void storeC(float* p, float v) { *p = v; }
__device__ __forceinline__ void storeC(__hip_bfloat16* p, float v) { *p = __float2bfloat16(v); }

template <typename OutT, int EPI, bool BATCH_X>
__global__ __launch_bounds__(256, 3) void gemm_bt_kernel(
    const __hip_bfloat16* __restrict__ A,   // [M][lda], k-contiguous
    const __hip_bfloat16* __restrict__ Bm,  // [N][ldb], k-contiguous
    OutT* __restrict__ C,                   // [M][ldc]
    __hip_bfloat16* __restrict__ vtOut,     // EPI==2 only
    int K, int lda, int ldb, int ldc,
    long sA, long sB, long sC, float scale) {
    __shared__ char smem[32768];
    char* AsB = smem;
    char* BsB = smem + 16384;

    int b, tileM, tileN;
    if (BATCH_X) {  // batch on x => batch == linear%8 == XCD id (L2 locality)
        b = blockIdx.x; tileN = blockIdx.y * 128; tileM = blockIdx.z * 128;
    } else {
        b = blockIdx.z; tileN = blockIdx.x * 128; tileM = blockIdx.y * 128;
    }
    A  += (long)b * sA;
    Bm += (long)b * sB;
    C  += (long)b * sC;

    const int tid  = threadIdx.x;
    const int lane = tid & 63;
    const int wave = tid >> 6;
    const int wm = (wave >> 1) * 64;
    const int wn = (wave & 1) * 64;
    const int quad = lane >> 4;
    const int lrow = lane & 15;

    // staging: thread covers 16B; row = tid>>3 (0..31), swizzled col chunk
    const int srow = tid >> 3;
    const int schunk = (tid & 7) ^ (srow & 7);
    const int scol = schunk << 3;

    f32x4 acc[4][4];
    const f32x4 zero = {0.f, 0.f, 0.f, 0.f};
#pragma unroll
    for (int i = 0; i < 4; ++i)
#pragma unroll
        for (int j = 0; j < 4; ++j) acc[i][j] = zero;

    const __hip_bfloat16* gA = A + (long)(tileM + srow) * lda + scol;
    const __hip_bfloat16* gB = Bm + (long)(tileN + srow) * ldb + scol;
    const int ldsOff = tid * 16;  // bytes; dest = wave-uniform base + lane*16

    typedef const __attribute__((address_space(1))) void* gp;
    typedef __attribute__((address_space(3))) void* sp;

    const int swa = (lrow & 7) << 4;  // XOR byte swizzle for fragment reads

    for (int k0 = 0; k0 < K; k0 += 64) {
        __syncthreads();
#pragma unroll
        for (int j = 0; j < 4; ++j)
            __builtin_amdgcn_global_load_lds((gp)(gA + (long)(j * 32) * lda + k0),
                                             (sp)(AsB + j * 4096 + ldsOff), 16, 0, 0);
#pragma unroll
        for (int j = 0; j < 4; ++j)
            __builtin_amdgcn_global_load_lds((gp)(gB + (long)(j * 32) * ldb + k0),
                                             (sp)(BsB + j * 4096 + ldsOff), 16, 0, 0);
        __syncthreads();

#pragma unroll
        for (int kk = 0; kk < 2; ++kk) {
            s16x8 af[4], bfr[4];
#pragma unroll
            for (int i = 0; i < 4; ++i)
                af[i] = *(const s16x8*)(AsB + (wm + i * 16 + lrow) * 128 +
                                        ((((kk << 2) | quad) << 4) ^ swa));
#pragma unroll
            for (int j = 0; j < 4; ++j)
                bfr[j] = *(const s16x8*)(BsB + (wn + j * 16 + lrow) * 128 +
                                         ((((kk << 2) | quad) << 4) ^ swa));
#pragma unroll
            for (int i = 0; i < 4; ++i)
#pragma unroll
                for (int j = 0; j < 4; ++j)
                    acc[i][j] = __builtin_amdgcn_mfma_f32_16x16x32_bf16(af[i], bfr[j], acc[i][j], 0, 0, 0);
        }
    }

    // ---------------- epilogue ----------------
    if (EPI == 2 && tileN >= NQK) {
        // V tile: transpose through LDS, store to vt[b'][d][s].
        // LDS layout: [128 d][16 chunks of 16B], chunk XOR-swizzled by (d&15).
        __syncthreads();  // all waves done with As/Bs before reuse
        char* T = smem;   // 128*256 = 32768 bytes, exact fit
#pragma unroll
        for (int i = 0; i < 4; ++i) {
#pragma unroll
            for (int j = 0; j < 4; ++j) {
                const int d = wn + j * 16 + lrow;        // local col (V feature)
                const int s = wm + i * 16 + quad * 4;    // granule of 4 rows
                bf16x4 g;
#pragma unroll
                for (int r = 0; r < 4; ++r) g.h[r] = __float2bfloat16(acc[i][j][r]);
                const int c = s >> 3;                    // 16B chunk index
                const int off = d * 256 + (((c ^ (d & 15)) << 4) | ((s & 4) << 1));
                *(bf16x4*)(T + off) = g;
            }
        }
        __syncthreads();
        // coalesced readout: thread t -> d' = t>>1, half = t&1 (64 s-elems)
        const int dl = tid >> 1, half = tid & 1;
        const long bb = tileM >> 11;                 // batch from row block
        const int s0 = tileM & (NS - 1);
        const long dg = (long)(tileN - NQK) + dl;    // V feature 0..767
        __hip_bfloat16* dst = vtOut + (bb * ND + dg) * NS + s0;
#pragma unroll
        for (int cc = 0; cc < 8; ++cc) {
            const int c2 = half * 8 + cc;
            s16x8 val = *(const s16x8*)(T + dl * 256 + ((c2 ^ (dl & 15)) << 4));
            *(s16x8*)(dst + c2 * 8) = val;
        }
        return;
    }

    // normal path: D[row=quad*4+r][col=lane&15] per 16x16 tile
#pragma unroll
    for (int i = 0; i < 4; ++i) {
#pragma unroll
        for (int j = 0; j < 4; ++j) {
            const int col = tileN + wn + j * 16 + lrow;
#pragma unroll
            for (int r = 0; r < 4; ++r) {
                const int row = tileM + wm + i * 16 + quad * 4 + r;
                storeC(C + (long)row * ldc + col, acc[i][j][r] * scale);
            }
        }
    }
}

// ---------------- softmax: wave per row over 2048 bf16, no barriers ----------------
__global__ __launch_bounds__(256) void softmax_kernel(__hip_bfloat16* __restrict__ P) {
    const long row = (long)blockIdx.x * 4 + (threadIdx.x >> 6);
    const int lane = threadIdx.x & 63;
    __hip_bfloat16* p = P + row * NS;

    bf16x8 raw[4];
    float v[32];
#pragma unroll
    for (int c = 0; c < 4; ++c) raw[c] = *(const bf16x8*)(p + c * 512 + lane * 8);
#pragma unroll
    for (int c = 0; c < 4; ++c)
#pragma unroll
        for (int i = 0; i < 8; ++i) v[c * 8 + i] = __bfloat162float(raw[c].h[i]);

    float m = v[0];
#pragma unroll
    for (int i = 1; i < 32; ++i) m = fmaxf(m, v[i]);
#pragma unroll
    for (int off = 1; off < 64; off <<= 1) m = fmaxf(m, __shfl_xor(m, off));

    float s = 0.f;
#pragma unroll
    for (int i = 0; i < 32; ++i) {
        v[i] = __expf(v[i] - m);
        s += v[i];
    }
#pragma unroll
    for (int off = 1; off < 64; off <<= 1) s += __shfl_xor(s, off);
    const float inv = 1.f / s;

#pragma unroll
    for (int c = 0; c < 4; ++c) {
        bf16x8 o;
#pragma unroll
        for (int i = 0; i < 8; ++i) o.h[i] = __float2bfloat16(v[c * 8 + i] * inv);
        *(bf16x8*)(p + c * 512 + lane * 8) = o;
    }
}

// ---------------- launch ----------------
extern "C" void kernel_launch(void* const* d_in, const int* in_sizes, int n_in,
                              void* d_out, int out_size, void* d_ws, size_t ws_size,
                              hipStream_t stream) {
    const float* x   = (const float*)d_in[0];  // [8][2048][768]
    const float* QKV = (const float*)d_in[1];  // [3][768][768]
    float* out = (float*)d_out;                // [8][2048][768]

    uint8_t* ws = (uint8_t*)d_ws;
    constexpr size_t XB_BYTES  = (size_t)MTOT * ND * 2;     // 25.2M
    constexpr size_t WT_BYTES  = (size_t)3 * ND * ND * 2;   //  3.5M
    constexpr size_t QKV_BYTES = (size_t)MTOT * NQK * 2;    // 50.3M (Q|K only)
    constexpr size_t VT_BYTES  = (size_t)NB * ND * NS * 2;  // 25.2M
    __hip_bfloat16* xb    = (__hip_bfloat16*)(ws);
    __hip_bfloat16* Wt    = (__hip_bfloat16*)(ws + XB_BYTES);
    __hip_bfloat16* qkvb  = (__hip_bfloat16*)(ws + XB_BYTES + WT_BYTES);
    __hip_bfloat16* vt    = (__hip_bfloat16*)(ws + XB_BYTES + WT_BYTES + QKV_BYTES);
    __hip_bfloat16* probs = (__hip_bfloat16*)(ws + XB_BYTES + WT_BYTES + QKV_BYTES + VT_BYTES);

    const float scale = 0.03608439182435161f;  // 1/sqrt(768)

    // 1. preprocess: xb = bf16(x); Wt = bf16(W^T)
    preprocess_kernel<<<CVT_BLOCKS + 1728, 256, 0, stream>>>(x, xb, QKV, Wt);
    // 2. fused QKV projection: Q|K -> qkvb [16384][1536]; V -> vt[b][d][s]
    gemm_bt_kernel<__hip_bfloat16, 2, false><<<dim3(2304 / 128, MTOT / 128, 1), 256, 0, stream>>>(
        xb, Wt, qkvb, vt, ND, ND, ND, NQK, 0, 0, 0, 1.0f);
    // 3. logits = scale * Q K^T  (per batch; batch on x for XCD-L2 locality)
    gemm_bt_kernel<__hip_bfloat16, 0, true><<<dim3(NB, NS / 128, NS / 128), 256, 0, stream>>>(
        qkvb, qkvb + ND, probs, nullptr, ND, NQK, NQK, NS,
        (long)NS * NQK, (long)NS * NQK, (long)NS * NS, scale);
    // 4. softmax rows in place (wave per row)
    softmax_kernel<<<MTOT / 4, 256, 0, stream>>>(probs);
    // 5. out = P @ V  (fp32 out)
    gemm_bt_kernel<float, 1, true><<<dim3(NB, ND / 128, NS / 128), 256, 0, stream>>>(
        probs, vt, out, nullptr, NS, NS, NS, ND,
        (long)NS * NS, (long)ND * NS, (long)NS * ND, 1.0f);
}